// Round 6
// baseline (24920.886 us; speedup 1.0000x reference)
//
#include <hip/hip_runtime.h>
#include <hip/hip_fp16.h>
#include <cstdint>

#define N_TOT 30000
#define E_TOT 120000
#define G_TOT 1000

typedef unsigned short u16;
typedef unsigned int u32;
typedef __attribute__((ext_vector_type(8))) short short8;
typedef __attribute__((ext_vector_type(4))) float f32x4;

#define AS1 __attribute__((address_space(1)))
#define AS3 __attribute__((address_space(3)))

// async global->LDS, 16B per lane. LDS dest must be wave-uniform base + lane*16.
static __device__ __forceinline__ void gload_lds16(const void* g, void* l) {
  __builtin_amdgcn_global_load_lds((AS1 void*)(uintptr_t)g,
                                   (AS3 void*)(uint32_t)(uintptr_t)l, 16, 0, 0);
}

static __device__ __forceinline__ u16 f2bf(float f) {
  uint32_t u = __float_as_uint(f);
  uint32_t r = (u + 0x7fffu + ((u >> 16) & 1u)) >> 16;  // RTNE
  return (u16)r;
}
static __device__ __forceinline__ float bf2f(u16 v) {
  return __uint_as_float((uint32_t)v << 16);
}

// f16 pack/unpack through the official HIP fp16 API (no raw builtins).
static __device__ __forceinline__ u32 packh2(float a, float b) {
  __half2 h = __floats2half2_rn(a, b);
  return __builtin_bit_cast(u32, h);
}
static __device__ __forceinline__ float2 unph2(u32 v) {
  return __half22float2(__builtin_bit_cast(__half2, v));
}

// ---------------- deg (in-edges per dst), graph counts, src out-degree ------
__global__ void prep_kernel(const int* __restrict__ ei, const int* __restrict__ batch,
                            float* __restrict__ deg, float* __restrict__ gcnt,
                            int* __restrict__ sd) {
  int t = blockIdx.x * 256 + threadIdx.x;
  if (t < E_TOT) {
    atomicAdd(&deg[ei[E_TOT + t]], 1.0f);
    atomicAdd(&sd[ei[t]], 1);
  }
  if (t < N_TOT) atomicAdd(&gcnt[batch[t]], 1.0f);
}

// ---------------- exclusive scan of src out-degree (single block) ----------
__global__ void scan_kernel(const int* __restrict__ sd, int* __restrict__ off) {
  __shared__ int buf[1024];
  __shared__ int carry;
  const int t = threadIdx.x;
  if (t == 0) carry = 0;
  __syncthreads();
  for (int base = 0; base < N_TOT; base += 1024) {
    int v = base + t;
    int x = (v < N_TOT) ? sd[v] : 0;
    buf[t] = x;
    __syncthreads();
    for (int o = 1; o < 1024; o <<= 1) {
      int y = (t >= o) ? buf[t - o] : 0;
      __syncthreads();
      buf[t] += y;
      __syncthreads();
    }
    if (v < N_TOT) off[v] = carry + buf[t] - x;
    __syncthreads();
    if (t == 0) carry += buf[1023];
    __syncthreads();
  }
  if (t == 0) off[N_TOT] = carry;
}

// ---------------- counting-sort edges by src -------------------------------
__global__ void scatter_kernel(const int* __restrict__ ei, const float* __restrict__ ea,
                               const int* __restrict__ off, int* __restrict__ cur,
                               int* __restrict__ src_s, int* __restrict__ dst_s,
                               float* __restrict__ ea_s) {
  int e = blockIdx.x * 256 + threadIdx.x;
  if (e >= E_TOT) return;
  int s = ei[e];
  int pos = off[s] + atomicAdd(&cur[s], 1);
  src_s[pos] = s;
  dst_s[pos] = ei[E_TOT + e];
#pragma unroll
  for (int j = 0; j < 8; ++j) ea_s[(size_t)pos * 8 + j] = ea[(size_t)e * 8 + j];
}

// ---------------- permute ew2 -> Wp[(kb*2+oh)*128 + c][i] bf16 -------------
// c-mapping for offset-immediate fold: c = o'*4 + kc (k = kb*4+kc, o = oh*32+o')
__global__ void cvt_wp(const float* __restrict__ ew2, u16* __restrict__ wp,
                       int K, int DINp) {
  int idx = blockIdx.x * 256 + threadIdx.x;  // (kbh, c)
  int c = idx & 127, kbh = idx >> 7;
  int kb = kbh >> 1, oh = kbh & 1;
  int k = kb * 4 + (c & 3), o = oh * 32 + (c >> 2);
  const float* src = ew2 + (size_t)k * (DINp * 64) + o;
  u16* dst = wp + (size_t)idx * DINp;
  for (int i = 0; i < DINp; ++i) dst[i] = f2bf(src[(size_t)i * 64]);
}

// ---------------- transpose ew1 -> ew1t[k][8] ------------------------------
__global__ void cvt_w1(const float* __restrict__ ew1, float* __restrict__ ew1t, int K) {
  int i = blockIdx.x * 256 + threadIdx.x;
  if (i >= K * 8) return;
  int k = i >> 3, j = i & 7;
  ew1t[i] = ew1[(size_t)j * K + k];
}

// ---------------- fused: M-build (MFMA bf16) + per-edge f16 fold + scatter --
// grid = 469 node-groups x 2 o-halves; block = 512 threads (8 waves).
// Double-buffered Wp staging: slab kb+1 prefetched during step kb, kept in
// flight across barriers via counted vmcnt + raw s_barrier (T3/T4 pattern).
template <int DIN>
__global__ __launch_bounds__(512, 4) void fused_conv(
    const u16* __restrict__ Wp, const float* __restrict__ ew1t,
    const float* __restrict__ eb1, const float* __restrict__ eb2,
    const float* __restrict__ xin, const float* __restrict__ eas,
    const int* __restrict__ src_s, const int* __restrict__ dst_s,
    const int* __restrict__ node_off, float* __restrict__ agg, int K) {
  constexpr int KF = DIN / 32;  // mfma k-fragments (i-dim)
  constexpr int NB = DIN / 8;   // 16B granules per Wp row
  constexpr int PF = NB / 4;    // gloads per thread per slab (2 or 1)
  constexpr int SLAB = 128 * DIN * 2;  // slab bytes
  constexpr int MROW = 272;
  constexpr int L_XB = 0;                  // [64][DIN] u16 (bf16)
  constexpr int L_WP = 64 * DIN * 2;       // 2 x [128][DIN] u16 (dbuf, swizzled)
  constexpr int L_MS = L_WP + 2 * SLAB;    // [64][MROW] f16 M
  constexpr int L_HS = L_MS + 64 * MROW;   // [512][8B] f16 kc-quads
  constexpr int L_VL = L_HS + 4096;        // [512] int
  __shared__ char smem[L_VL + 2048];

  const int t = threadIdx.x;
  const int lane = t & 63, wave = t >> 6;
  const int u = lane & 15, q = lane >> 4;
  const int grp = blockIdx.x >> 1, oh = blockIdx.x & 1;
  const int v0 = grp * 64;
  const int e0 = node_off[v0];
  const int v1 = (v0 + 64 < N_TOT) ? v0 + 64 : N_TOT;
  int Eblk = node_off[v1] - e0;
  if (Eblk > 512) Eblk = 512;

  // stage x group (bf16)
  {
    int row = t >> 3, i0 = (t & 7) * (DIN / 8);
    u16* xb = (u16*)(smem + L_XB) + row * DIN + i0;
    int vg = v0 + row;
#pragma unroll
    for (int j = 0; j < DIN / 8; ++j)
      xb[j] = (vg < N_TOT) ? f2bf(xin[(size_t)vg * DIN + i0 + j]) : (u16)0;
  }
  // edge attrs -> REGISTERS
  f32x4 ea0 = (f32x4){0.f, 0.f, 0.f, 0.f}, ea1 = (f32x4){0.f, 0.f, 0.f, 0.f};
  {
    int vl = 0;
    if (t < Eblk) {
      const f32x4* s = (const f32x4*)(eas + (size_t)(e0 + t) * 8);
      ea0 = s[0];
      ea1 = s[1];
      vl = src_s[e0 + t] - v0;
    }
    ((int*)(smem + L_VL))[t] = vl;
  }
  __syncthreads();

  // cache x fragments (B-operand: B[k=i][n=v])
  short8 bfr[4][KF];
#pragma unroll
  for (int vt = 0; vt < 4; ++vt)
#pragma unroll
    for (int kf = 0; kf < KF; ++kf)
      bfr[vt][kf] =
          *(const short8*)(smem + L_XB + ((vt * 16 + u) * DIN + (kf * 4 + q) * 8) * 2);

  // fold task registers: task (slot = t>>1 + p*256, oq = t&1)
  const int oq = t & 1;
  int mbase[2], hbase[2], vls[2], slotp[2];
#pragma unroll
  for (int p = 0; p < 2; ++p) {
    int s = (t >> 1) + p * 256;
    slotp[p] = s;
    int vl = ((int*)(smem + L_VL))[s];
    vls[p] = vl;
    mbase[p] = L_MS + vl * MROW + oq * 136;
    hbase[p] = L_HS + s * 8;
  }
  float acc[2][16];
#pragma unroll
  for (int p = 0; p < 2; ++p)
#pragma unroll
    for (int j = 0; j < 16; ++j) acc[p][j] = 0.f;

  const int nsteps = K >> 2;

  auto stage = [&](int kbs, int buf) {
    const u16* gsl = Wp + (size_t)(kbs * 2 + oh) * (128 * DIN);
    char* dst = smem + L_WP + buf * SLAB;
#pragma unroll
    for (int j = 0; j < PF; ++j) {
      int s = j * 512 + t;
      int c = s / NB, ib = s % NB;
      gload_lds16(gsl + (c * NB + (ib ^ (c & (NB - 1)))) * 8, dst + s * 16);
    }
  };

  // prologue: stage slab 0 into buf 0
  stage(0, 0);

  for (int kb = 0; kb < nsteps; ++kb) {
    const int cur = kb & 1;
    // s2: H chunk for own slot (ea in regs; ew1t row k is wave-uniform)
    {
      const int kk = kb * 4;
      float hv[4];
#pragma unroll
      for (int kc = 0; kc < 4; ++kc) {
        int k = kk + kc;
        const float* wr = ew1t + (size_t)k * 8;
        float a = eb1[k];
        a += ea0.x * wr[0] + ea0.y * wr[1] + ea0.z * wr[2] + ea0.w * wr[3];
        a += ea1.x * wr[4] + ea1.y * wr[5] + ea1.z * wr[6] + ea1.w * wr[7];
        hv[kc] = a > 0.f ? a : 0.f;
      }
      uint2 hw;
      hw.x = packh2(hv[0], hv[1]);
      hw.y = packh2(hv[2], hv[3]);
      *(uint2*)(smem + L_HS + t * 8) = hw;
    }
    // prefetch next slab into the other buffer; keep it in flight (vmcnt=PF)
    if (kb + 1 < nsteps) {
      stage(kb + 1, cur ^ 1);
      if constexpr (PF == 2)
        asm volatile("s_waitcnt vmcnt(2) lgkmcnt(0)" ::: "memory");
      else
        asm volatile("s_waitcnt vmcnt(1) lgkmcnt(0)" ::: "memory");
    } else {
      asm volatile("s_waitcnt vmcnt(0) lgkmcnt(0)" ::: "memory");
    }
    __builtin_amdgcn_s_barrier();  // slab kb + Hs now visible to all waves

    // s4: MFMA  M rows c = wave*16 + q*4 + j  (c = o'*4+kc => o' = wave*4+q, kc = j)
    {
      const char* bufC = smem + L_WP + cur * SLAB;
      f32x4 acm[4];
#pragma unroll
      for (int vt = 0; vt < 4; ++vt) acm[vt] = (f32x4){0.f, 0.f, 0.f, 0.f};
      const int crow = wave * 16 + u;
#pragma unroll
      for (int kf = 0; kf < KF; ++kf) {
        short8 afr = *(const short8*)(
            bufC + (crow * DIN + (((kf * 4 + q) ^ (crow & (NB - 1))) * 8)) * 2);
#pragma unroll
        for (int vt = 0; vt < 4; ++vt)
          acm[vt] = __builtin_amdgcn_mfma_f32_16x16x32_bf16(afr, bfr[vt][kf], acm[vt], 0, 0, 0);
      }
      // s5: lane holds kc=0..3 for (v = vt*16+u, o' = wave*4+q): 2 pkrtz, b64 write
      const int opr = wave * 4 + q;
      const int off = opr * 8 + (opr >> 4) * 8;  // oq-split at +136
#pragma unroll
      for (int vt = 0; vt < 4; ++vt) {
        int v = vt * 16 + u;
        uint2 pk;
        pk.x = packh2(acm[vt].x, acm[vt].y);
        pk.y = packh2(acm[vt].z, acm[vt].w);
        *(uint2*)(smem + L_MS + v * MROW + off) = pk;
      }
    }
    asm volatile("s_waitcnt lgkmcnt(0)" ::: "memory");
    __builtin_amdgcn_s_barrier();  // M visible; prefetch still in flight

    // s7: fold, offset-immediate ds_read_b128 + f16->f32 mix FMAs
#pragma unroll
    for (int p = 0; p < 2; ++p) {
      if (wave * 32 + p * 256 < Eblk) {
        uint2 hu = *(const uint2*)(smem + hbase[p]);
        float2 h01 = unph2(hu.x);
        float2 h23 = unph2(hu.y);
        const char* mr = smem + mbase[p];
#pragma unroll
        for (int m = 0; m < 8; ++m) {
          uint4 m8 = *(const uint4*)(mr + m * 16);
          float2 a0 = unph2(m8.x);  // o'=2m   kc0,1
          float2 a1 = unph2(m8.y);  // o'=2m   kc2,3
          float2 b0 = unph2(m8.z);  // o'=2m+1 kc0,1
          float2 b1 = unph2(m8.w);  // o'=2m+1 kc2,3
          float s0 = acc[p][2 * m], s1 = acc[p][2 * m + 1];
          s0 += a0.x * h01.x;
          s0 += a0.y * h01.y;
          s0 += a1.x * h23.x;
          s0 += a1.y * h23.y;
          s1 += b0.x * h01.x;
          s1 += b0.y * h01.y;
          s1 += b1.x * h23.x;
          s1 += b1.y * h23.y;
          acc[p][2 * m] = s0;
          acc[p][2 * m + 1] = s1;
        }
      }
    }
    asm volatile("s_waitcnt lgkmcnt(0)" ::: "memory");
    __builtin_amdgcn_s_barrier();  // fold done before next-step HS/MS overwrite
  }
  __syncthreads();  // full drain before tail

  // bias term bt[v][o'] = sum_i x[v,i]*eb2[i*64 + oh*32 + o']  (into Ms area)
  {
    int v = t >> 3, o4 = (t & 7) * 4;
    f32x4 acb = (f32x4){0.f, 0.f, 0.f, 0.f};
    const u16* xb = (const u16*)(smem + L_XB) + v * DIN;
    const float* ep = eb2 + oh * 32 + o4;
    for (int i = 0; i < DIN; ++i) {
      float xv = bf2f(xb[i]);
      f32x4 w4 = *(const f32x4*)(ep + (size_t)i * 64);
      acb += xv * w4;
    }
    *(f32x4*)(smem + L_MS + (v * 32 + o4) * 4) = acb;
  }
  __syncthreads();

  // scatter: agg[dst, oh*32 + oq*16 + 0..15] += msg + bt
#pragma unroll
  for (int p = 0; p < 2; ++p) {
    int slot = slotp[p];
    if (slot < Eblk) {
      int d = dst_s[e0 + slot];
      float* ap = agg + (size_t)d * 64 + oh * 32 + oq * 16;
      const float* bt = (const float*)(smem + L_MS) + vls[p] * 32 + oq * 16;
#pragma unroll
      for (int j = 0; j < 16; ++j) atomicAdd(ap + j, acc[p][j] + bt[j]);
    }
  }
}

// ---------------- out = relu(agg/deg + x@root + cb) ----------------
__global__ void node_update(const float* __restrict__ agg, const float* __restrict__ deg,
                            const float* __restrict__ xin, const float* __restrict__ root,
                            const float* __restrict__ cbv, float* __restrict__ xout,
                            int din) {
  __shared__ float rl[4096];
  const int t = threadIdx.x;
  for (int i = t; i < din * 64; i += 256) rl[i] = root[i];
  __syncthreads();
  const int o = t & 63;
  const int n = blockIdx.x * 4 + (t >> 6);
  if (n >= N_TOT) return;
  float acc = cbv[o];
  for (int i = 0; i < din; ++i) acc += xin[(size_t)n * din + i] * rl[i * 64 + o];
  float d = deg[n];
  d = d > 1.f ? d : 1.f;
  acc += agg[(size_t)n * 64 + o] / d;
  xout[(size_t)n * 64 + o] = acc > 0.f ? acc : 0.f;
}

// ---------------- graph sum pool ----------------
__global__ void pool_kernel(const float* __restrict__ x3, const int* __restrict__ batch,
                            float* __restrict__ gsum) {
  int t = blockIdx.x * 256 + threadIdx.x;
  if (t >= N_TOT * 64) return;
  int n = t >> 6, o = t & 63;
  atomicAdd(&gsum[(size_t)batch[n] * 64 + o], x3[t]);
}

// ---------------- readout MLP ----------------
__global__ void readout_kernel(const float* __restrict__ gsum, const float* __restrict__ gcnt,
                               const float* __restrict__ mw1, const float* __restrict__ mb1,
                               const float* __restrict__ mw2, const float* __restrict__ mb2,
                               float* __restrict__ out) {
  __shared__ float gv[4][64];
  const int t = threadIdx.x;
  const int o = t & 63, loc = t >> 6;
  const int g = blockIdx.x * 4 + loc;
  float v = 0.f;
  if (g < G_TOT) {
    float c = gcnt[g];
    c = c > 1.f ? c : 1.f;
    v = gsum[(size_t)g * 64 + o] / c;
  }
  gv[loc][o] = v;
  __syncthreads();
  float acc = mb1[o];
  for (int i = 0; i < 64; ++i) acc += gv[loc][i] * mw1[i * 64 + o];
  acc = acc > 0.f ? acc : 0.f;
  float p = acc * mw2[o];
#pragma unroll
  for (int off = 32; off > 0; off >>= 1) p += __shfl_down(p, off, 64);
  if (o == 0 && g < G_TOT) out[g] = p + mb2[0];
}

extern "C" void kernel_launch(void* const* d_in, const int* in_sizes, int n_in,
                              void* d_out, int out_size, void* d_ws, size_t ws_size,
                              hipStream_t stream) {
  const float* x     = (const float*)d_in[0];
  const int*   ei    = (const int*)d_in[1];
  const float* ea    = (const float*)d_in[2];
  const int*   batch = (const int*)d_in[3];
  const float* ew1[3] = {(const float*)d_in[4],  (const float*)d_in[10], (const float*)d_in[16]};
  const float* eb1[3] = {(const float*)d_in[5],  (const float*)d_in[11], (const float*)d_in[17]};
  const float* ew2[3] = {(const float*)d_in[6],  (const float*)d_in[12], (const float*)d_in[18]};
  const float* eb2[3] = {(const float*)d_in[7],  (const float*)d_in[13], (const float*)d_in[19]};
  const float* root[3] = {(const float*)d_in[8],  (const float*)d_in[14], (const float*)d_in[20]};
  const float* cbv[3]  = {(const float*)d_in[9],  (const float*)d_in[15], (const float*)d_in[21]};
  const float* mw1 = (const float*)d_in[22];
  const float* mb1 = (const float*)d_in[23];
  const float* mw2 = (const float*)d_in[24];
  const float* mb2 = (const float*)d_in[25];
  float* out = (float*)d_out;

  char* p = (char*)d_ws;
  auto carve = [&p](size_t bytes) {
    char* r = p;
    p += (bytes + 255) & ~(size_t)255;
    return r;
  };
  u16*   wp   = (u16*)carve((size_t)4096 * 64 * 64 * 2);  // permuted ew2, per-layer
  float* ew1t = (float*)carve((size_t)4096 * 8 * 4);      // transposed ew1, per-layer
  float* x1   = (float*)carve((size_t)N_TOT * 64 * 4);
  float* x2   = (float*)carve((size_t)N_TOT * 64 * 4);
  float* x3   = (float*)carve((size_t)N_TOT * 64 * 4);
  float* agg  = (float*)carve((size_t)N_TOT * 64 * 4);
  float* deg  = (float*)carve((size_t)N_TOT * 4);
  float* gsum = (float*)carve((size_t)G_TOT * 64 * 4);
  float* gcnt = (float*)carve((size_t)G_TOT * 4);
  int*   sd   = (int*)carve((size_t)N_TOT * 4);
  int*   noff = (int*)carve((size_t)(N_TOT + 1) * 4);
  int*   cur  = (int*)carve((size_t)N_TOT * 4);
  int*   srcs = (int*)carve((size_t)E_TOT * 4);
  int*   dsts = (int*)carve((size_t)E_TOT * 4);
  float* eass = (float*)carve((size_t)E_TOT * 8 * 4);

  hipMemsetAsync(deg, 0, (size_t)N_TOT * 4, stream);
  hipMemsetAsync(gsum, 0, (size_t)G_TOT * 64 * 4, stream);
  hipMemsetAsync(gcnt, 0, (size_t)G_TOT * 4, stream);
  hipMemsetAsync(sd, 0, (size_t)N_TOT * 4, stream);
  hipMemsetAsync(cur, 0, (size_t)N_TOT * 4, stream);

  prep_kernel<<<(E_TOT + 255) / 256, 256, 0, stream>>>(ei, batch, deg, gcnt, sd);
  scan_kernel<<<1, 1024, 0, stream>>>(sd, noff);
  scatter_kernel<<<(E_TOT + 255) / 256, 256, 0, stream>>>(ei, ea, noff, cur, srcs, dsts, eass);

  const float* xin_l[3]  = {x, x1, x2};
  float*       xout_l[3] = {x1, x2, x3};
  const int Ks[3]   = {2048, 4096, 4096};
  const int dins[3] = {32, 64, 64};
  const int grid_fused = ((N_TOT + 63) / 64) * 2;  // 938

  for (int L = 0; L < 3; ++L) {
    const int K = Ks[L], din = dins[L];
    cvt_wp<<<(K * 64) / 256, 256, 0, stream>>>(ew2[L], wp, K, din);
    cvt_w1<<<(K * 8 + 255) / 256, 256, 0, stream>>>(ew1[L], ew1t, K);
    hipMemsetAsync(agg, 0, (size_t)N_TOT * 64 * 4, stream);
    if (din == 32)
      fused_conv<32><<<grid_fused, 512, 0, stream>>>(wp, ew1t, eb1[L], eb2[L], xin_l[L],
                                                     eass, srcs, dsts, noff, agg, K);
    else
      fused_conv<64><<<grid_fused, 512, 0, stream>>>(wp, ew1t, eb1[L], eb2[L], xin_l[L],
                                                     eass, srcs, dsts, noff, agg, K);
    node_update<<<(N_TOT + 3) / 4, 256, 0, stream>>>(agg, deg, xin_l[L], root[L], cbv[L],
                                                     xout_l[L], din);
  }
  pool_kernel<<<(N_TOT * 64 + 255) / 256, 256, 0, stream>>>(x3, batch, gsum);
  readout_kernel<<<(G_TOT + 3) / 4, 256, 0, stream>>>(gsum, gcnt, mw1, mb1, mw2, mb2, out);
}

// Round 7
// 15023.723 us; speedup vs baseline: 1.6588x; 1.6588x over previous
//
#include <hip/hip_runtime.h>
#include <hip/hip_fp16.h>
#include <cstdint>

#define N_TOT 30000
#define E_TOT 120000
#define G_TOT 1000

typedef unsigned short u16;
typedef unsigned int u32;
typedef __attribute__((ext_vector_type(8))) short short8;
typedef __attribute__((ext_vector_type(4))) float f32x4;

#define AS1 __attribute__((address_space(1)))
#define AS3 __attribute__((address_space(3)))

// async global->LDS, 16B per lane. LDS dest must be wave-uniform base + lane*16.
static __device__ __forceinline__ void gload_lds16(const void* g, void* l) {
  __builtin_amdgcn_global_load_lds((AS1 void*)(uintptr_t)g,
                                   (AS3 void*)(uint32_t)(uintptr_t)l, 16, 0, 0);
}

static __device__ __forceinline__ u16 f2bf(float f) {
  uint32_t u = __float_as_uint(f);
  uint32_t r = (u + 0x7fffu + ((u >> 16) & 1u)) >> 16;  // RTNE
  return (u16)r;
}
static __device__ __forceinline__ float bf2f(u16 v) {
  return __uint_as_float((uint32_t)v << 16);
}

// f16 pack/unpack through the official HIP fp16 API (compile-proven r5/r6).
static __device__ __forceinline__ u32 packh2(float a, float b) {
  __half2 h = __floats2half2_rn(a, b);
  return __builtin_bit_cast(u32, h);
}
static __device__ __forceinline__ float2 unph2(u32 v) {
  return __half22float2(__builtin_bit_cast(__half2, v));
}

// ---------------- deg (in-edges per dst), graph counts, src out-degree ------
__global__ void prep_kernel(const int* __restrict__ ei, const int* __restrict__ batch,
                            float* __restrict__ deg, float* __restrict__ gcnt,
                            int* __restrict__ sd) {
  int t = blockIdx.x * 256 + threadIdx.x;
  if (t < E_TOT) {
    atomicAdd(&deg[ei[E_TOT + t]], 1.0f);
    atomicAdd(&sd[ei[t]], 1);
  }
  if (t < N_TOT) atomicAdd(&gcnt[batch[t]], 1.0f);
}

// ---------------- exclusive scan of src out-degree (single block) ----------
__global__ void scan_kernel(const int* __restrict__ sd, int* __restrict__ off) {
  __shared__ int buf[1024];
  __shared__ int carry;
  const int t = threadIdx.x;
  if (t == 0) carry = 0;
  __syncthreads();
  for (int base = 0; base < N_TOT; base += 1024) {
    int v = base + t;
    int x = (v < N_TOT) ? sd[v] : 0;
    buf[t] = x;
    __syncthreads();
    for (int o = 1; o < 1024; o <<= 1) {
      int y = (t >= o) ? buf[t - o] : 0;
      __syncthreads();
      buf[t] += y;
      __syncthreads();
    }
    if (v < N_TOT) off[v] = carry + buf[t] - x;
    __syncthreads();
    if (t == 0) carry += buf[1023];
    __syncthreads();
  }
  if (t == 0) off[N_TOT] = carry;
}

// ---------------- counting-sort edges by src -------------------------------
__global__ void scatter_kernel(const int* __restrict__ ei, const float* __restrict__ ea,
                               const int* __restrict__ off, int* __restrict__ cur,
                               int* __restrict__ src_s, int* __restrict__ dst_s,
                               float* __restrict__ ea_s) {
  int e = blockIdx.x * 256 + threadIdx.x;
  if (e >= E_TOT) return;
  int s = ei[e];
  int pos = off[s] + atomicAdd(&cur[s], 1);
  src_s[pos] = s;
  dst_s[pos] = ei[E_TOT + e];
#pragma unroll
  for (int j = 0; j < 8; ++j) ea_s[(size_t)pos * 8 + j] = ea[(size_t)e * 8 + j];
}

// ---------------- permute ew2 -> Wp[(kb*2+oh)*128 + c][i] bf16 -------------
// c = kc*32 + o' with k = kb*4+kc, o = oh*32+o'  (r3 mapping)
__global__ void cvt_wp(const float* __restrict__ ew2, u16* __restrict__ wp,
                       int K, int DINp) {
  int idx = blockIdx.x * 256 + threadIdx.x;  // (kbh, c)
  int c = idx & 127, kbh = idx >> 7;
  int kb = kbh >> 1, oh = kbh & 1;
  int k = kb * 4 + (c >> 5), o = oh * 32 + (c & 31);
  const float* src = ew2 + (size_t)k * (DINp * 64) + o;
  u16* dst = wp + (size_t)idx * DINp;
  for (int i = 0; i < DINp; ++i) dst[i] = f2bf(src[(size_t)i * 64]);
}

// ---------------- transpose ew1 -> ew1t[k][8] ------------------------------
__global__ void cvt_w1(const float* __restrict__ ew1, float* __restrict__ ew1t, int K) {
  int i = blockIdx.x * 256 + threadIdx.x;
  if (i >= K * 8) return;
  int k = i >> 3, j = i & 7;
  ew1t[i] = ew1[(size_t)j * K + k];
}

// ---------------- fused: M-build (MFMA bf16) + own-slot f16 fold + scatter --
// grid = 469 node-groups x 2 o-halves; block = 512 threads (8 waves).
// r3 skeleton: 3 syncthreads/step, vmcnt0 drain, M rows 256B, XOR granule
// swizzle by (v&7). Changes vs r3: M stored f16 (packh2), fold is own-slot
// (thread t folds edge t, all 32 o'), H kept in 4 f32 regs (no HS LDS).
template <int DIN>
__global__ __launch_bounds__(512, 4) void fused_conv(
    const u16* __restrict__ Wp, const float* __restrict__ ew1t,
    const float* __restrict__ eb1, const float* __restrict__ eb2,
    const float* __restrict__ xin, const float* __restrict__ eas,
    const int* __restrict__ src_s, const int* __restrict__ dst_s,
    const int* __restrict__ node_off, float* __restrict__ agg, int K) {
  constexpr int KF = DIN / 32;  // mfma k-fragments (i-dim)
  constexpr int NB = DIN / 8;   // 16B granules per Wp row
  constexpr int L_XB = 0;                     // [64][DIN] u16 (bf16)
  constexpr int L_WP = 64 * DIN * 2;          // [128][DIN] u16 (swizzled)
  constexpr int L_MS = L_WP + 128 * DIN * 2;  // [64][128] f16 (granule-swizzled)
  __shared__ char smem[L_MS + 16384];

  const int t = threadIdx.x;
  const int lane = t & 63, wave = t >> 6;
  const int u = lane & 15, q = lane >> 4;
  const int grp = blockIdx.x >> 1, oh = blockIdx.x & 1;
  const int v0 = grp * 64;
  const int e0 = node_off[v0];
  const int v1 = (v0 + 64 < N_TOT) ? v0 + 64 : N_TOT;
  int Eblk = node_off[v1] - e0;
  if (Eblk > 512) Eblk = 512;

  // stage x group (bf16)
  {
    int row = t >> 3, i0 = (t & 7) * (DIN / 8);
    u16* xb = (u16*)(smem + L_XB) + row * DIN + i0;
    int vg = v0 + row;
#pragma unroll
    for (int j = 0; j < DIN / 8; ++j)
      xb[j] = (vg < N_TOT) ? f2bf(xin[(size_t)vg * DIN + i0 + j]) : (u16)0;
  }
  // own edge attrs + src-local id -> REGISTERS
  f32x4 ea0 = (f32x4){0.f, 0.f, 0.f, 0.f}, ea1 = (f32x4){0.f, 0.f, 0.f, 0.f};
  int vl = 0;
  if (t < Eblk) {
    const f32x4* s = (const f32x4*)(eas + (size_t)(e0 + t) * 8);
    ea0 = s[0];
    ea1 = s[1];
    vl = src_s[e0 + t] - v0;
  }
  const int vofs = L_MS + vl * 256;
  const int vswz = vl & 7;
  __syncthreads();

  // cache x fragments (B-operand: B[k=i][n=v])
  short8 bfr[4][KF];
#pragma unroll
  for (int vt = 0; vt < 4; ++vt)
#pragma unroll
    for (int kf = 0; kf < KF; ++kf)
      bfr[vt][kf] =
          *(const short8*)(smem + L_XB + ((vt * 16 + u) * DIN + (kf * 4 + q) * 8) * 2);

  float acc[32];
#pragma unroll
  for (int j = 0; j < 32; ++j) acc[j] = 0.f;

  const size_t slab = (size_t)128 * DIN;
  const int nsteps = K >> 2;
  for (int kb = 0; kb < nsteps; ++kb) {
    // s1: async stage Wp slab (swizzled granules)
    const u16* gsl = Wp + (size_t)(kb * 2 + oh) * slab;
#pragma unroll
    for (int j = 0; j < NB / 4; ++j) {
      int s = j * 512 + t;
      int c = s / NB, ib = s % NB;
      gload_lds16(gsl + (c * NB + (ib ^ (c & (NB - 1)))) * 8, smem + L_WP + s * 16);
    }
    // s2: H for own edge -> 4 f32 registers (no LDS round-trip)
    float hv[4];
    {
      const int kk = kb * 4;
#pragma unroll
      for (int kc = 0; kc < 4; ++kc) {
        int k = kk + kc;
        const float* wr = ew1t + (size_t)k * 8;
        float a = eb1[k];
        a += ea0.x * wr[0] + ea0.y * wr[1] + ea0.z * wr[2] + ea0.w * wr[3];
        a += ea1.x * wr[4] + ea1.y * wr[5] + ea1.z * wr[6] + ea1.w * wr[7];
        hv[kc] = a > 0.f ? a : 0.f;
      }
    }
    __syncthreads();  // drains gload

    // s4: MFMA  M[c = wave*16+q*4+j][v = vt*16+u]
    {
      f32x4 acm[4];
#pragma unroll
      for (int vt = 0; vt < 4; ++vt) acm[vt] = (f32x4){0.f, 0.f, 0.f, 0.f};
      const int crow = wave * 16 + u;
#pragma unroll
      for (int kf = 0; kf < KF; ++kf) {
        short8 afr = *(const short8*)(
            smem + L_WP + (crow * DIN + (((kf * 4 + q) ^ (crow & (NB - 1))) * 8)) * 2);
#pragma unroll
        for (int vt = 0; vt < 4; ++vt)
          acm[vt] = __builtin_amdgcn_mfma_f32_16x16x32_bf16(afr, bfr[vt][kf], acm[vt], 0, 0, 0);
      }
      // s5: write M chunk as f16 (packh2), 16B-granule swizzle by v (r3 addrs)
#pragma unroll
      for (int vt = 0; vt < 4; ++vt) {
        int v = vt * 16 + u;
        uint2 pk;
        pk.x = packh2(acm[vt].x, acm[vt].y);
        pk.y = packh2(acm[vt].z, acm[vt].w);
        int bbG = ((wave << 1) | (q >> 1)) ^ (v & 7);
        *(uint2*)(smem + L_MS + v * 256 + bbG * 16 + (q & 1) * 8) = pk;
      }
    }
    __syncthreads();

    // s7: own-slot fold — 16 granules of own row, (float)f16 * f32 FMAs
    if (t < Eblk) {
#pragma unroll
      for (int kc = 0; kc < 4; ++kc) {
        float h = hv[kc];
#pragma unroll
        for (int g = 0; g < 4; ++g) {
          int bb = (kc * 4 + g) ^ vswz;
          uint4 m8 = *(const uint4*)(smem + vofs + bb * 16);
          float2 p0 = unph2(m8.x);
          float2 p1 = unph2(m8.y);
          float2 p2 = unph2(m8.z);
          float2 p3 = unph2(m8.w);
          acc[g * 8 + 0] += h * p0.x;
          acc[g * 8 + 1] += h * p0.y;
          acc[g * 8 + 2] += h * p1.x;
          acc[g * 8 + 3] += h * p1.y;
          acc[g * 8 + 4] += h * p2.x;
          acc[g * 8 + 5] += h * p2.y;
          acc[g * 8 + 6] += h * p3.x;
          acc[g * 8 + 7] += h * p3.y;
        }
      }
    }
    __syncthreads();
  }

  // bias term bt[v][o'] = sum_i x[v,i]*eb2[i*64 + oh*32 + o']  (into Ms area)
  {
    int v = t >> 3, o4 = (t & 7) * 4;
    f32x4 acb = (f32x4){0.f, 0.f, 0.f, 0.f};
    const u16* xb = (const u16*)(smem + L_XB) + v * DIN;
    const float* ep = eb2 + oh * 32 + o4;
    for (int i = 0; i < DIN; ++i) {
      float xv = bf2f(xb[i]);
      f32x4 w4 = *(const f32x4*)(ep + (size_t)i * 64);
      acb += xv * w4;
    }
    *(f32x4*)(smem + L_MS + (v * 32 + o4) * 4) = acb;
  }
  __syncthreads();

  // scatter: agg[dst, oh*32 + 0..31] += acc + bt
  if (t < Eblk) {
    int d = dst_s[e0 + t];
    float* ap = agg + (size_t)d * 64 + oh * 32;
    const float* bt = (const float*)(smem + L_MS) + vl * 32;
#pragma unroll
    for (int j = 0; j < 32; ++j) atomicAdd(ap + j, acc[j] + bt[j]);
  }
}

// ---------------- out = relu(agg/deg + x@root + cb) ----------------
__global__ void node_update(const float* __restrict__ agg, const float* __restrict__ deg,
                            const float* __restrict__ xin, const float* __restrict__ root,
                            const float* __restrict__ cbv, float* __restrict__ xout,
                            int din) {
  __shared__ float rl[4096];
  const int t = threadIdx.x;
  for (int i = t; i < din * 64; i += 256) rl[i] = root[i];
  __syncthreads();
  const int o = t & 63;
  const int n = blockIdx.x * 4 + (t >> 6);
  if (n >= N_TOT) return;
  float acc = cbv[o];
  for (int i = 0; i < din; ++i) acc += xin[(size_t)n * din + i] * rl[i * 64 + o];
  float d = deg[n];
  d = d > 1.f ? d : 1.f;
  acc += agg[(size_t)n * 64 + o] / d;
  xout[(size_t)n * 64 + o] = acc > 0.f ? acc : 0.f;
}

// ---------------- graph sum pool ----------------
__global__ void pool_kernel(const float* __restrict__ x3, const int* __restrict__ batch,
                            float* __restrict__ gsum) {
  int t = blockIdx.x * 256 + threadIdx.x;
  if (t >= N_TOT * 64) return;
  int n = t >> 6, o = t & 63;
  atomicAdd(&gsum[(size_t)batch[n] * 64 + o], x3[t]);
}

// ---------------- readout MLP ----------------
__global__ void readout_kernel(const float* __restrict__ gsum, const float* __restrict__ gcnt,
                               const float* __restrict__ mw1, const float* __restrict__ mb1,
                               const float* __restrict__ mw2, const float* __restrict__ mb2,
                               float* __restrict__ out) {
  __shared__ float gv[4][64];
  const int t = threadIdx.x;
  const int o = t & 63, loc = t >> 6;
  const int g = blockIdx.x * 4 + loc;
  float v = 0.f;
  if (g < G_TOT) {
    float c = gcnt[g];
    c = c > 1.f ? c : 1.f;
    v = gsum[(size_t)g * 64 + o] / c;
  }
  gv[loc][o] = v;
  __syncthreads();
  float acc = mb1[o];
  for (int i = 0; i < 64; ++i) acc += gv[loc][i] * mw1[i * 64 + o];
  acc = acc > 0.f ? acc : 0.f;
  float p = acc * mw2[o];
#pragma unroll
  for (int off = 32; off > 0; off >>= 1) p += __shfl_down(p, off, 64);
  if (o == 0 && g < G_TOT) out[g] = p + mb2[0];
}

extern "C" void kernel_launch(void* const* d_in, const int* in_sizes, int n_in,
                              void* d_out, int out_size, void* d_ws, size_t ws_size,
                              hipStream_t stream) {
  const float* x     = (const float*)d_in[0];
  const int*   ei    = (const int*)d_in[1];
  const float* ea    = (const float*)d_in[2];
  const int*   batch = (const int*)d_in[3];
  const float* ew1[3] = {(const float*)d_in[4],  (const float*)d_in[10], (const float*)d_in[16]};
  const float* eb1[3] = {(const float*)d_in[5],  (const float*)d_in[11], (const float*)d_in[17]};
  const float* ew2[3] = {(const float*)d_in[6],  (const float*)d_in[12], (const float*)d_in[18]};
  const float* eb2[3] = {(const float*)d_in[7],  (const float*)d_in[13], (const float*)d_in[19]};
  const float* root[3] = {(const float*)d_in[8],  (const float*)d_in[14], (const float*)d_in[20]};
  const float* cbv[3]  = {(const float*)d_in[9],  (const float*)d_in[15], (const float*)d_in[21]};
  const float* mw1 = (const float*)d_in[22];
  const float* mb1 = (const float*)d_in[23];
  const float* mw2 = (const float*)d_in[24];
  const float* mb2 = (const float*)d_in[25];
  float* out = (float*)d_out;

  char* p = (char*)d_ws;
  auto carve = [&p](size_t bytes) {
    char* r = p;
    p += (bytes + 255) & ~(size_t)255;
    return r;
  };
  u16*   wp   = (u16*)carve((size_t)4096 * 64 * 64 * 2);  // permuted ew2, per-layer
  float* ew1t = (float*)carve((size_t)4096 * 8 * 4);      // transposed ew1, per-layer
  float* x1   = (float*)carve((size_t)N_TOT * 64 * 4);
  float* x2   = (float*)carve((size_t)N_TOT * 64 * 4);
  float* x3   = (float*)carve((size_t)N_TOT * 64 * 4);
  float* agg  = (float*)carve((size_t)N_TOT * 64 * 4);
  float* deg  = (float*)carve((size_t)N_TOT * 4);
  float* gsum = (float*)carve((size_t)G_TOT * 64 * 4);
  float* gcnt = (float*)carve((size_t)G_TOT * 4);
  int*   sd   = (int*)carve((size_t)N_TOT * 4);
  int*   noff = (int*)carve((size_t)(N_TOT + 1) * 4);
  int*   cur  = (int*)carve((size_t)N_TOT * 4);
  int*   srcs = (int*)carve((size_t)E_TOT * 4);
  int*   dsts = (int*)carve((size_t)E_TOT * 4);
  float* eass = (float*)carve((size_t)E_TOT * 8 * 4);

  hipMemsetAsync(deg, 0, (size_t)N_TOT * 4, stream);
  hipMemsetAsync(gsum, 0, (size_t)G_TOT * 64 * 4, stream);
  hipMemsetAsync(gcnt, 0, (size_t)G_TOT * 4, stream);
  hipMemsetAsync(sd, 0, (size_t)N_TOT * 4, stream);
  hipMemsetAsync(cur, 0, (size_t)N_TOT * 4, stream);

  prep_kernel<<<(E_TOT + 255) / 256, 256, 0, stream>>>(ei, batch, deg, gcnt, sd);
  scan_kernel<<<1, 1024, 0, stream>>>(sd, noff);
  scatter_kernel<<<(E_TOT + 255) / 256, 256, 0, stream>>>(ei, ea, noff, cur, srcs, dsts, eass);

  const float* xin_l[3]  = {x, x1, x2};
  float*       xout_l[3] = {x1, x2, x3};
  const int Ks[3]   = {2048, 4096, 4096};
  const int dins[3] = {32, 64, 64};
  const int grid_fused = ((N_TOT + 63) / 64) * 2;  // 938

  for (int L = 0; L < 3; ++L) {
    const int K = Ks[L], din = dins[L];
    cvt_wp<<<(K * 64) / 256, 256, 0, stream>>>(ew2[L], wp, K, din);
    cvt_w1<<<(K * 8 + 255) / 256, 256, 0, stream>>>(ew1[L], ew1t, K);
    hipMemsetAsync(agg, 0, (size_t)N_TOT * 64 * 4, stream);
    if (din == 32)
      fused_conv<32><<<grid_fused, 512, 0, stream>>>(wp, ew1t, eb1[L], eb2[L], xin_l[L],
                                                     eass, srcs, dsts, noff, agg, K);
    else
      fused_conv<64><<<grid_fused, 512, 0, stream>>>(wp, ew1t, eb1[L], eb2[L], xin_l[L],
                                                     eass, srcs, dsts, noff, agg, K);
    node_update<<<(N_TOT + 3) / 4, 256, 0, stream>>>(agg, deg, xin_l[L], root[L], cbv[L],
                                                     xout_l[L], din);
  }
  pool_kernel<<<(N_TOT * 64 + 255) / 256, 256, 0, stream>>>(x3, batch, gsum);
  readout_kernel<<<(G_TOT + 3) / 4, 256, 0, stream>>>(gsum, gcnt, mw1, mb1, mw2, mb2, out);
}